// Round 1
// baseline (552.755 us; speedup 1.0000x reference)
//
#include <hip/hip_runtime.h>

#define NROWS 131072
#define GRID1 1024
#define ITERS 8   // 1024 blocks * 8 iters * 4 waves * 4 rows = 131072

__device__ __forceinline__ float dot4(float4 a, float4 b) {
    return fmaf(a.x, b.x, fmaf(a.y, b.y, fmaf(a.z, b.z, a.w * b.w)));
}

// LDS layout. Wp rows: tier0 rows 0..63, tier1 rows 64..95, tier2 rows 96..111, stride 68
// (68 = 4 mod 8 -> 8 lanes per bank-quad, distinct addresses = bandwidth floor).
// Waug: 64 rows x 116 cols: [M0(64) | M1(32) | M2(16) | WcBu0,1,2 | bc], stride 116 (also 4 mod 8).
struct Smem {
    float Wp[112 * 68];
    float bpb[112];
    float Waug[64 * 116];
    float qbuf[4][4][64];     // [wave][row][k]
    float qpbuf[4][4][112];   // [wave][row][qp0(64)|qp1(32)|qp2(16)]
    float rbuf[4][4][116];    // [wave][row][racc0|racc1|racc2|c0,c1,c2,1.0]
};

// One tier of: dot(mem,qp) -> segmented sum -> max/denominator reductions ->
// unnormalized retrieved accumulation -> write to rbuf. Returns den (= 1/conf).
template<int SEG>
__device__ __forceinline__ float tier_proc(int lane, float4 m, const float* qpbase, float* rbase) {
    float4 qpv = *reinterpret_cast<const float4*>(qpbase + 4 * (lane & (SEG - 1)));
    float p = dot4(m, qpv);                       // partial sim (scale folded into Wp/bp)
#pragma unroll
    for (int off = 1; off < SEG; off <<= 1) p += __shfl_xor(p, off, 64);
    float mx = p;
#pragma unroll
    for (int off = SEG; off < 64; off <<= 1) mx = fmaxf(mx, __shfl_xor(mx, off, 64));
    float e = __expf(p - mx);
    float den = e;
#pragma unroll
    for (int off = SEG; off < 64; off <<= 1) den += __shfl_xor(den, off, 64);
    float4 rv = make_float4(m.x * e, m.y * e, m.z * e, m.w * e);
#pragma unroll
    for (int off = SEG; off < 64; off <<= 1) {
        rv.x += __shfl_xor(rv.x, off, 64);
        rv.y += __shfl_xor(rv.y, off, 64);
        rv.z += __shfl_xor(rv.z, off, 64);
        rv.w += __shfl_xor(rv.w, off, 64);
    }
    if (lane < SEG) *reinterpret_cast<float4*>(rbase + 4 * lane) = rv;
    return den;
}

// Prep: Waug[o][c] = [Wc@Wu0 | Wc@Wu1 | Wc@Wu2 | Wc@bu0 | Wc@bu1 | Wc@bu2 | bc]
__global__ __launch_bounds__(128) void prep_kernel(
    const float* __restrict__ Wu0, const float* __restrict__ Wu1, const float* __restrict__ Wu2,
    const float* __restrict__ bu0, const float* __restrict__ bu1, const float* __restrict__ bu2,
    const float* __restrict__ Wc,  const float* __restrict__ bc,  float* __restrict__ waug) {
    int o = blockIdx.x;
    int c = threadIdx.x;
    if (c >= 116) return;
    float acc = 0.0f;
    if (c < 112) {
        const float* wu; int d, dim;
        if (c < 64)      { wu = Wu0; d = c;      dim = 64; }
        else if (c < 96) { wu = Wu1; d = c - 64; dim = 32; }
        else             { wu = Wu2; d = c - 96; dim = 16; }
        for (int h = 0; h < 64; ++h) acc = fmaf(Wc[o * 64 + h], wu[h * dim + d], acc);
    } else if (c < 115) {
        const float* bu = (c == 112) ? bu0 : (c == 113) ? bu1 : bu2;
        for (int h = 0; h < 64; ++h) acc = fmaf(Wc[o * 64 + h], bu[h], acc);
    } else {
        acc = bc[o];
    }
    waug[o * 116 + c] = acc;
}

__global__ __launch_bounds__(256, 2) void retrieval_kernel(
    const float* __restrict__ query,
    const float* __restrict__ mem0, const float* __restrict__ mem1, const float* __restrict__ mem2,
    const float* __restrict__ Wp0, const float* __restrict__ bp0,
    const float* __restrict__ Wp1, const float* __restrict__ bp1,
    const float* __restrict__ Wp2, const float* __restrict__ bp2,
    const float* __restrict__ waug, float* __restrict__ out) {
    __shared__ Smem sm;
    const int t = threadIdx.x;
    const int wv = t >> 6;
    const int lane = t & 63;

    // ---- stage weights (scale 1/sqrt(dim) folded into Wp and bp) ----
    for (int idx = t; idx < 4096; idx += 256) { int r = idx >> 6, k = idx & 63; sm.Wp[r * 68 + k] = Wp0[idx] * 0.125f; }
    for (int idx = t; idx < 2048; idx += 256) { int r = idx >> 6, k = idx & 63; sm.Wp[(64 + r) * 68 + k] = Wp1[idx] * 0.17677669529663687f; }
    for (int idx = t; idx < 1024; idx += 256) { int r = idx >> 6, k = idx & 63; sm.Wp[(96 + r) * 68 + k] = Wp2[idx] * 0.25f; }
    if (t < 112) {
        float sc = (t < 64) ? 0.125f : (t < 96) ? 0.17677669529663687f : 0.25f;
        float v  = (t < 64) ? bp0[t] : (t < 96) ? bp1[t - 64] : bp2[t - 96];
        sm.bpb[t] = v * sc;
    }
    for (int idx = t; idx < 7424; idx += 256) sm.Waug[idx] = waug[idx];
    __syncthreads();

    const float4* w0p = reinterpret_cast<const float4*>(&sm.Wp[lane * 68]);
    const float4* w1p = reinterpret_cast<const float4*>(&sm.Wp[(64 + (lane & 31)) * 68]);
    const float4* w2p = reinterpret_cast<const float4*>(&sm.Wp[(96 + (lane & 15)) * 68]);
    const float4* war = reinterpret_cast<const float4*>(&sm.Waug[lane * 116]);
    const float b0 = sm.bpb[lane];
    const float b1 = sm.bpb[64 + (lane & 31)];
    const float b2 = sm.bpb[96 + (lane & 15)];

    const int blockRow0 = blockIdx.x * (ITERS * 16);

    for (int it = 0; it < ITERS; ++it) {
        const int r0 = blockRow0 + it * 16 + wv * 4;

        // ---- load q rows + stage to LDS; prefetch all mem tiles for 4 rows ----
        float4 mpre[3][4];
#pragma unroll
        for (int j = 0; j < 4; ++j) {
            sm.qbuf[wv][j][lane] = query[(r0 + j) * 64 + lane];
        }
#pragma unroll
        for (int j = 0; j < 4; ++j) {
            mpre[0][j] = reinterpret_cast<const float4*>(mem0 + (size_t)(r0 + j) * 256)[lane];
            mpre[1][j] = reinterpret_cast<const float4*>(mem1 + (size_t)(r0 + j) * 256)[lane];
            mpre[2][j] = reinterpret_cast<const float4*>(mem2 + (size_t)(r0 + j) * 256)[lane];
        }

        // ---- down-projections for all 3 tiers, 4 rows (weights amortized over rows) ----
        float a0[4], a1[4], a2[4];
#pragma unroll
        for (int j = 0; j < 4; ++j) { a0[j] = b0; a1[j] = b1; a2[j] = b2; }
#pragma unroll 4
        for (int kb = 0; kb < 16; ++kb) {
            float4 w0 = w0p[kb], w1 = w1p[kb], w2 = w2p[kb];
#pragma unroll
            for (int j = 0; j < 4; ++j) {
                float4 qv = reinterpret_cast<const float4*>(&sm.qbuf[wv][j][0])[kb];
                a0[j] = fmaf(w0.x, qv.x, fmaf(w0.y, qv.y, fmaf(w0.z, qv.z, fmaf(w0.w, qv.w, a0[j]))));
                a1[j] = fmaf(w1.x, qv.x, fmaf(w1.y, qv.y, fmaf(w1.z, qv.z, fmaf(w1.w, qv.w, a1[j]))));
                a2[j] = fmaf(w2.x, qv.x, fmaf(w2.y, qv.y, fmaf(w2.z, qv.z, fmaf(w2.w, qv.w, a2[j]))));
            }
        }
#pragma unroll
        for (int j = 0; j < 4; ++j) {
            sm.qpbuf[wv][j][lane] = a0[j];
            if (lane < 32) sm.qpbuf[wv][j][64 + lane] = a1[j];
            if (lane < 16) sm.qpbuf[wv][j][96 + lane] = a2[j];
        }

        // ---- per-row: sims -> softmax(max/den only) -> unnormalized retrieved; conf combine ----
        float cf0[4], cf1[4], cf2[4];
#pragma unroll
        for (int j = 0; j < 4; ++j) {
            float* qp = &sm.qpbuf[wv][j][0];
            float* rb = &sm.rbuf[wv][j][0];
            float den0 = tier_proc<16>(lane, mpre[0][j], qp, rb);
            float den1 = tier_proc<8>(lane, mpre[1][j], qp + 64, rb + 64);
            float den2 = tier_proc<4>(lane, mpre[2][j], qp + 96, rb + 96);
            // conf_i = 1/den_i; softmax over 3 confs
            float c0 = __frcp_rn(den0), c1 = __frcp_rn(den1), c2 = __frcp_rn(den2);
            float cm = fmaxf(c0, fmaxf(c1, c2));
            float e0 = __expf(c0 - cm), e1 = __expf(c1 - cm), e2 = __expf(c2 - cm);
            float ics = __frcp_rn(e0 + e1 + e2);
            float cw0 = e0 * ics, cw1 = e1 * ics, cw2 = e2 * ics;
            cf0[j] = cw0 * c0;   // cw_i / den_i  (normalizes racc)
            cf1[j] = cw1 * c1;
            cf2[j] = cw2 * c2;
            float ext = (lane == 0) ? cw0 : (lane == 1) ? cw1 : (lane == 2) ? cw2 : 1.0f;
            if (lane < 4) rb[112 + lane] = ext;
        }

        // ---- fused epilogue: out = sum over 116 augmented columns (weights amortized) ----
        float t0[4] = {0, 0, 0, 0}, t1[4] = {0, 0, 0, 0}, t2[4] = {0, 0, 0, 0}, t3[4];
#pragma unroll 4
        for (int cb = 0; cb < 16; ++cb) {
            float4 w = war[cb];
#pragma unroll
            for (int j = 0; j < 4; ++j) {
                float4 rv = reinterpret_cast<const float4*>(&sm.rbuf[wv][j][0])[cb];
                t0[j] = fmaf(w.x, rv.x, fmaf(w.y, rv.y, fmaf(w.z, rv.z, fmaf(w.w, rv.w, t0[j]))));
            }
        }
#pragma unroll 4
        for (int cb = 16; cb < 24; ++cb) {
            float4 w = war[cb];
#pragma unroll
            for (int j = 0; j < 4; ++j) {
                float4 rv = reinterpret_cast<const float4*>(&sm.rbuf[wv][j][0])[cb];
                t1[j] = fmaf(w.x, rv.x, fmaf(w.y, rv.y, fmaf(w.z, rv.z, fmaf(w.w, rv.w, t1[j]))));
            }
        }
#pragma unroll
        for (int cb = 24; cb < 28; ++cb) {
            float4 w = war[cb];
#pragma unroll
            for (int j = 0; j < 4; ++j) {
                float4 rv = reinterpret_cast<const float4*>(&sm.rbuf[wv][j][0])[cb];
                t2[j] = fmaf(w.x, rv.x, fmaf(w.y, rv.y, fmaf(w.z, rv.z, fmaf(w.w, rv.w, t2[j]))));
            }
        }
        {
            float4 w = war[28];
#pragma unroll
            for (int j = 0; j < 4; ++j) {
                float4 rv = reinterpret_cast<const float4*>(&sm.rbuf[wv][j][0])[28];
                t3[j] = dot4(w, rv);
            }
        }
#pragma unroll
        for (int j = 0; j < 4; ++j) {
            out[(r0 + j) * 64 + lane] =
                fmaf(cf0[j], t0[j], fmaf(cf1[j], t1[j], fmaf(cf2[j], t2[j], t3[j])));
        }
    }
}

extern "C" void kernel_launch(void* const* d_in, const int* in_sizes, int n_in,
                              void* d_out, int out_size, void* d_ws, size_t ws_size,
                              hipStream_t stream) {
    const float* query = (const float*)d_in[0];
    const float* mem0  = (const float*)d_in[1];
    const float* mem1  = (const float*)d_in[2];
    const float* mem2  = (const float*)d_in[3];
    const float* Wp0   = (const float*)d_in[4];
    const float* bp0   = (const float*)d_in[5];
    const float* Wu0   = (const float*)d_in[6];
    const float* bu0   = (const float*)d_in[7];
    const float* Wp1   = (const float*)d_in[8];
    const float* bp1   = (const float*)d_in[9];
    const float* Wu1   = (const float*)d_in[10];
    const float* bu1   = (const float*)d_in[11];
    const float* Wp2   = (const float*)d_in[12];
    const float* bp2   = (const float*)d_in[13];
    const float* Wu2   = (const float*)d_in[14];
    const float* bu2   = (const float*)d_in[15];
    const float* Wc    = (const float*)d_in[16];
    const float* bc    = (const float*)d_in[17];
    float* waug = (float*)d_ws;   // 64*116 floats = 29696 B
    float* outp = (float*)d_out;

    prep_kernel<<<64, 128, 0, stream>>>(Wu0, Wu1, Wu2, bu0, bu1, bu2, Wc, bc, waug);
    retrieval_kernel<<<GRID1, 256, 0, stream>>>(query, mem0, mem1, mem2,
                                                Wp0, bp0, Wp1, bp1, Wp2, bp2,
                                                waug, outp);
}

// Round 2
// 536.783 us; speedup vs baseline: 1.0298x; 1.0298x over previous
//
#include <hip/hip_runtime.h>

#define NROWS 131072
#define GRID1 1024
#define ITERS 8   // 1024 blocks * 8 iters * 4 waves * 4 rows = 131072

// DPP controls (row = 16 lanes on CDNA)
#define DPP_XOR1 0xB1   // quad_perm(1,0,3,2)
#define DPP_XOR2 0x4E   // quad_perm(2,3,0,1)
#define DPP_HMIR 0x141  // row_half_mirror = xor 7 (within 8)
#define DPP_ROR1 0x121
#define DPP_ROR2 0x122
#define DPP_ROR4 0x124
#define DPP_ROR8 0x128

template<int C>
__device__ __forceinline__ float fdpp(float x) {
    return __int_as_float(__builtin_amdgcn_mov_dpp(__float_as_int(x), C, 0xF, 0xF, true));
}

__device__ __forceinline__ float dot4(float4 a, float4 b) {
    return fmaf(a.x, b.x, fmaf(a.y, b.y, fmaf(a.z, b.z, a.w * b.w)));
}

// LDS layout. Wp rows: tier0 rows 0..63, tier1 64..95, tier2 96..111, stride 68.
// Waug: 64 rows x 116 cols: [M0(64) | M1(32) | M2(16) | WcBu0,1,2 | bc], stride 116.
struct Smem {
    float Wp[112 * 68];
    float bpb[112];
    float Waug[64 * 116];
    float qpbuf[4][4][112];   // [wave][row][qp0(64)|qp1(32)|qp2(16)]
    float rbuf[4][4][116];    // [wave][row][racc0|racc1|racc2|cw0,cw1,cw2,1.0]
};

// Tier 0: S=4, dim=64. Lane l holds m[s=l&3][4*(l>>2)..+3].
// sims reduce over stride-4 lanes (ror4,ror8 DPP + xor16,32 LDS);
// max/den/rv reduce over s = within quad (pure DPP). All lanes end with full r4.
__device__ __forceinline__ float tier0_proc(int lane, float4 m, const float* qp, float* rb) {
    float4 qv = *reinterpret_cast<const float4*>(qp + 4 * (lane >> 2));
    float p = dot4(m, qv);
    p += fdpp<DPP_ROR4>(p);
    p += fdpp<DPP_ROR8>(p);
    p += __shfl_xor(p, 16, 64);
    p += __shfl_xor(p, 32, 64);
    float mx = fmaxf(p, fdpp<DPP_XOR1>(p));
    mx = fmaxf(mx, fdpp<DPP_XOR2>(mx));
    float e = __expf(p - mx);
    float den = e + fdpp<DPP_XOR1>(e);
    den += fdpp<DPP_XOR2>(den);
    float4 rv = make_float4(m.x * e, m.y * e, m.z * e, m.w * e);
    rv.x += fdpp<DPP_XOR1>(rv.x); rv.y += fdpp<DPP_XOR1>(rv.y);
    rv.z += fdpp<DPP_XOR1>(rv.z); rv.w += fdpp<DPP_XOR1>(rv.w);
    rv.x += fdpp<DPP_XOR2>(rv.x); rv.y += fdpp<DPP_XOR2>(rv.y);
    rv.z += fdpp<DPP_XOR2>(rv.z); rv.w += fdpp<DPP_XOR2>(rv.w);
    if ((lane & 3) == 0) *reinterpret_cast<float4*>(rb + 4 * (lane >> 2)) = rv;
    return den;
}

// Tier 1: S=8, dim=32. Lane l holds m[s=l&7][4*(l>>3)..+3].
__device__ __forceinline__ float tier1_proc(int lane, float4 m, const float* qp, float* rb) {
    float4 qv = *reinterpret_cast<const float4*>(qp + 4 * (lane >> 3));
    float p = dot4(m, qv);
    p += fdpp<DPP_ROR8>(p);
    p += __shfl_xor(p, 16, 64);
    p += __shfl_xor(p, 32, 64);
    float mx = fmaxf(p, fdpp<DPP_XOR1>(p));
    mx = fmaxf(mx, fdpp<DPP_XOR2>(mx));
    mx = fmaxf(mx, fdpp<DPP_HMIR>(mx));
    float e = __expf(p - mx);
    float den = e + fdpp<DPP_XOR1>(e);
    den += fdpp<DPP_XOR2>(den);
    den += fdpp<DPP_HMIR>(den);
    float4 rv = make_float4(m.x * e, m.y * e, m.z * e, m.w * e);
    rv.x += fdpp<DPP_XOR1>(rv.x); rv.y += fdpp<DPP_XOR1>(rv.y);
    rv.z += fdpp<DPP_XOR1>(rv.z); rv.w += fdpp<DPP_XOR1>(rv.w);
    rv.x += fdpp<DPP_XOR2>(rv.x); rv.y += fdpp<DPP_XOR2>(rv.y);
    rv.z += fdpp<DPP_XOR2>(rv.z); rv.w += fdpp<DPP_XOR2>(rv.w);
    rv.x += fdpp<DPP_HMIR>(rv.x); rv.y += fdpp<DPP_HMIR>(rv.y);
    rv.z += fdpp<DPP_HMIR>(rv.z); rv.w += fdpp<DPP_HMIR>(rv.w);
    if ((lane & 7) == 0) *reinterpret_cast<float4*>(rb + 4 * (lane >> 3)) = rv;
    return den;
}

// Tier 2: S=16, dim=16. Lane l holds m[s=l&15][4*(l>>4)..+3].
__device__ __forceinline__ float tier2_proc(int lane, float4 m, const float* qp, float* rb) {
    float4 qv = *reinterpret_cast<const float4*>(qp + 4 * (lane >> 4));
    float p = dot4(m, qv);
    p += __shfl_xor(p, 16, 64);
    p += __shfl_xor(p, 32, 64);
    float mx = fmaxf(p, fdpp<DPP_ROR1>(p));
    mx = fmaxf(mx, fdpp<DPP_ROR2>(mx));
    mx = fmaxf(mx, fdpp<DPP_ROR4>(mx));
    mx = fmaxf(mx, fdpp<DPP_ROR8>(mx));
    float e = __expf(p - mx);
    float den = e + fdpp<DPP_ROR1>(e);
    den += fdpp<DPP_ROR2>(den);
    den += fdpp<DPP_ROR4>(den);
    den += fdpp<DPP_ROR8>(den);
    float4 rv = make_float4(m.x * e, m.y * e, m.z * e, m.w * e);
    rv.x += fdpp<DPP_ROR1>(rv.x); rv.y += fdpp<DPP_ROR1>(rv.y);
    rv.z += fdpp<DPP_ROR1>(rv.z); rv.w += fdpp<DPP_ROR1>(rv.w);
    rv.x += fdpp<DPP_ROR2>(rv.x); rv.y += fdpp<DPP_ROR2>(rv.y);
    rv.z += fdpp<DPP_ROR2>(rv.z); rv.w += fdpp<DPP_ROR2>(rv.w);
    rv.x += fdpp<DPP_ROR4>(rv.x); rv.y += fdpp<DPP_ROR4>(rv.y);
    rv.z += fdpp<DPP_ROR4>(rv.z); rv.w += fdpp<DPP_ROR4>(rv.w);
    rv.x += fdpp<DPP_ROR8>(rv.x); rv.y += fdpp<DPP_ROR8>(rv.y);
    rv.z += fdpp<DPP_ROR8>(rv.z); rv.w += fdpp<DPP_ROR8>(rv.w);
    if ((lane & 15) == 0) *reinterpret_cast<float4*>(rb + 4 * (lane >> 4)) = rv;
    return den;
}

// Prep: Waug[o][c] = [Wc@Wu0 | Wc@Wu1 | Wc@Wu2 | Wc@bu0 | Wc@bu1 | Wc@bu2 | bc]
__global__ __launch_bounds__(128) void prep_kernel(
    const float* __restrict__ Wu0, const float* __restrict__ Wu1, const float* __restrict__ Wu2,
    const float* __restrict__ bu0, const float* __restrict__ bu1, const float* __restrict__ bu2,
    const float* __restrict__ Wc,  const float* __restrict__ bc,  float* __restrict__ waug) {
    int o = blockIdx.x;
    int c = threadIdx.x;
    if (c >= 116) return;
    float acc = 0.0f;
    if (c < 112) {
        const float* wu; int d, dim;
        if (c < 64)      { wu = Wu0; d = c;      dim = 64; }
        else if (c < 96) { wu = Wu1; d = c - 64; dim = 32; }
        else             { wu = Wu2; d = c - 96; dim = 16; }
        for (int h = 0; h < 64; ++h) acc = fmaf(Wc[o * 64 + h], wu[h * dim + d], acc);
    } else if (c < 115) {
        const float* bu = (c == 112) ? bu0 : (c == 113) ? bu1 : bu2;
        for (int h = 0; h < 64; ++h) acc = fmaf(Wc[o * 64 + h], bu[h], acc);
    } else {
        acc = bc[o];
    }
    waug[o * 116 + c] = acc;
}

__global__ __launch_bounds__(256, 2) void retrieval_kernel(
    const float* __restrict__ query,
    const float* __restrict__ mem0, const float* __restrict__ mem1, const float* __restrict__ mem2,
    const float* __restrict__ Wp0, const float* __restrict__ bp0,
    const float* __restrict__ Wp1, const float* __restrict__ bp1,
    const float* __restrict__ Wp2, const float* __restrict__ bp2,
    const float* __restrict__ waug, float* __restrict__ out) {
    __shared__ Smem sm;
    const int t = threadIdx.x;
    const int wv = t >> 6;
    const int lane = t & 63;

    // ---- stage weights (scale 1/sqrt(dim) folded into Wp and bp) ----
    for (int idx = t; idx < 4096; idx += 256) { int r = idx >> 6, k = idx & 63; sm.Wp[r * 68 + k] = Wp0[idx] * 0.125f; }
    for (int idx = t; idx < 2048; idx += 256) { int r = idx >> 6, k = idx & 63; sm.Wp[(64 + r) * 68 + k] = Wp1[idx] * 0.17677669529663687f; }
    for (int idx = t; idx < 1024; idx += 256) { int r = idx >> 6, k = idx & 63; sm.Wp[(96 + r) * 68 + k] = Wp2[idx] * 0.25f; }
    if (t < 112) {
        float sc = (t < 64) ? 0.125f : (t < 96) ? 0.17677669529663687f : 0.25f;
        float v  = (t < 64) ? bp0[t] : (t < 96) ? bp1[t - 64] : bp2[t - 96];
        sm.bpb[t] = v * sc;
    }
    for (int idx = t; idx < 7424; idx += 256) sm.Waug[idx] = waug[idx];
    __syncthreads();

    const float4* w0p = reinterpret_cast<const float4*>(&sm.Wp[lane * 68]);
    const float4* w1p = reinterpret_cast<const float4*>(&sm.Wp[(64 + (lane & 31)) * 68]);
    const float4* w2p = reinterpret_cast<const float4*>(&sm.Wp[(96 + (lane & 15)) * 68]);
    const float4* war = reinterpret_cast<const float4*>(&sm.Waug[lane * 116]);
    const float b0 = sm.bpb[lane];
    const float b1 = sm.bpb[64 + (lane & 31)];
    const float b2 = sm.bpb[96 + (lane & 15)];

    // transposed lane->(s, d-quad) mem indices (lane-invariant across iters)
    const int mi0 = 16 * (lane & 3)  + (lane >> 2);
    const int mi1 = 8  * (lane & 7)  + (lane >> 3);
    const int mi2 = 4  * (lane & 15) + (lane >> 4);

    const int blockRow0 = blockIdx.x * (ITERS * 16);

    for (int it = 0; it < ITERS; ++it) {
        const int r0 = blockRow0 + it * 16 + wv * 4;

        // ---- prefetch mem tiles (transposed) for 4 rows ----
        float4 mpre[3][4];
#pragma unroll
        for (int j = 0; j < 4; ++j) {
            mpre[0][j] = reinterpret_cast<const float4*>(mem0 + (size_t)(r0 + j) * 256)[mi0];
            mpre[1][j] = reinterpret_cast<const float4*>(mem1 + (size_t)(r0 + j) * 256)[mi1];
            mpre[2][j] = reinterpret_cast<const float4*>(mem2 + (size_t)(r0 + j) * 256)[mi2];
        }

        // ---- down-projections: q via uniform global broadcast (L1), weights from LDS ----
        const float4* qg0 = reinterpret_cast<const float4*>(query + (size_t)(r0 + 0) * 64);
        const float4* qg1 = reinterpret_cast<const float4*>(query + (size_t)(r0 + 1) * 64);
        const float4* qg2 = reinterpret_cast<const float4*>(query + (size_t)(r0 + 2) * 64);
        const float4* qg3 = reinterpret_cast<const float4*>(query + (size_t)(r0 + 3) * 64);
        float a0[4], a1[4], a2[4];
#pragma unroll
        for (int j = 0; j < 4; ++j) { a0[j] = b0; a1[j] = b1; a2[j] = b2; }
#pragma unroll 4
        for (int kb = 0; kb < 16; ++kb) {
            float4 w0 = w0p[kb], w1 = w1p[kb], w2 = w2p[kb];
            float4 qv0 = qg0[kb], qv1 = qg1[kb], qv2 = qg2[kb], qv3 = qg3[kb];
            a0[0] = fmaf(w0.x, qv0.x, fmaf(w0.y, qv0.y, fmaf(w0.z, qv0.z, fmaf(w0.w, qv0.w, a0[0]))));
            a1[0] = fmaf(w1.x, qv0.x, fmaf(w1.y, qv0.y, fmaf(w1.z, qv0.z, fmaf(w1.w, qv0.w, a1[0]))));
            a2[0] = fmaf(w2.x, qv0.x, fmaf(w2.y, qv0.y, fmaf(w2.z, qv0.z, fmaf(w2.w, qv0.w, a2[0]))));
            a0[1] = fmaf(w0.x, qv1.x, fmaf(w0.y, qv1.y, fmaf(w0.z, qv1.z, fmaf(w0.w, qv1.w, a0[1]))));
            a1[1] = fmaf(w1.x, qv1.x, fmaf(w1.y, qv1.y, fmaf(w1.z, qv1.z, fmaf(w1.w, qv1.w, a1[1]))));
            a2[1] = fmaf(w2.x, qv1.x, fmaf(w2.y, qv1.y, fmaf(w2.z, qv1.z, fmaf(w2.w, qv1.w, a2[1]))));
            a0[2] = fmaf(w0.x, qv2.x, fmaf(w0.y, qv2.y, fmaf(w0.z, qv2.z, fmaf(w0.w, qv2.w, a0[2]))));
            a1[2] = fmaf(w1.x, qv2.x, fmaf(w1.y, qv2.y, fmaf(w1.z, qv2.z, fmaf(w1.w, qv2.w, a1[2]))));
            a2[2] = fmaf(w2.x, qv2.x, fmaf(w2.y, qv2.y, fmaf(w2.z, qv2.z, fmaf(w2.w, qv2.w, a2[2]))));
            a0[3] = fmaf(w0.x, qv3.x, fmaf(w0.y, qv3.y, fmaf(w0.z, qv3.z, fmaf(w0.w, qv3.w, a0[3]))));
            a1[3] = fmaf(w1.x, qv3.x, fmaf(w1.y, qv3.y, fmaf(w1.z, qv3.z, fmaf(w1.w, qv3.w, a1[3]))));
            a2[3] = fmaf(w2.x, qv3.x, fmaf(w2.y, qv3.y, fmaf(w2.z, qv3.z, fmaf(w2.w, qv3.w, a2[3]))));
        }
#pragma unroll
        for (int j = 0; j < 4; ++j) {
            sm.qpbuf[wv][j][lane] = a0[j];
            if (lane < 32) sm.qpbuf[wv][j][64 + lane] = a1[j];
            if (lane < 16) sm.qpbuf[wv][j][96 + lane] = a2[j];
        }

        // ---- per-row tiers (DPP reductions) + conf combine ----
        float cf0[4], cf1[4], cf2[4];
#pragma unroll
        for (int j = 0; j < 4; ++j) {
            float* qp = &sm.qpbuf[wv][j][0];
            float* rb = &sm.rbuf[wv][j][0];
            float den0 = tier0_proc(lane, mpre[0][j], qp, rb);
            float den1 = tier1_proc(lane, mpre[1][j], qp + 64, rb + 64);
            float den2 = tier2_proc(lane, mpre[2][j], qp + 96, rb + 96);
            float c0 = __frcp_rn(den0), c1 = __frcp_rn(den1), c2 = __frcp_rn(den2);
            float cm = fmaxf(c0, fmaxf(c1, c2));
            float e0 = __expf(c0 - cm), e1 = __expf(c1 - cm), e2 = __expf(c2 - cm);
            float ics = __frcp_rn(e0 + e1 + e2);
            float cw0 = e0 * ics, cw1 = e1 * ics, cw2 = e2 * ics;
            cf0[j] = cw0 * c0;
            cf1[j] = cw1 * c1;
            cf2[j] = cw2 * c2;
            float ext = (lane == 0) ? cw0 : (lane == 1) ? cw1 : (lane == 2) ? cw2 : 1.0f;
            if (lane < 4) rb[112 + lane] = ext;
        }

        // ---- fused epilogue: out = sum over 116 augmented columns (weights amortized) ----
        float t0[4] = {0, 0, 0, 0}, t1[4] = {0, 0, 0, 0}, t2[4] = {0, 0, 0, 0}, t3[4];
#pragma unroll 4
        for (int cb = 0; cb < 16; ++cb) {
            float4 w = war[cb];
#pragma unroll
            for (int j = 0; j < 4; ++j) {
                float4 rv = reinterpret_cast<const float4*>(&sm.rbuf[wv][j][0])[cb];
                t0[j] = fmaf(w.x, rv.x, fmaf(w.y, rv.y, fmaf(w.z, rv.z, fmaf(w.w, rv.w, t0[j]))));
            }
        }
#pragma unroll 4
        for (int cb = 16; cb < 24; ++cb) {
            float4 w = war[cb];
#pragma unroll
            for (int j = 0; j < 4; ++j) {
                float4 rv = reinterpret_cast<const float4*>(&sm.rbuf[wv][j][0])[cb];
                t1[j] = fmaf(w.x, rv.x, fmaf(w.y, rv.y, fmaf(w.z, rv.z, fmaf(w.w, rv.w, t1[j]))));
            }
        }
#pragma unroll
        for (int cb = 24; cb < 28; ++cb) {
            float4 w = war[cb];
#pragma unroll
            for (int j = 0; j < 4; ++j) {
                float4 rv = reinterpret_cast<const float4*>(&sm.rbuf[wv][j][0])[cb];
                t2[j] = fmaf(w.x, rv.x, fmaf(w.y, rv.y, fmaf(w.z, rv.z, fmaf(w.w, rv.w, t2[j]))));
            }
        }
        {
            float4 w = war[28];
#pragma unroll
            for (int j = 0; j < 4; ++j) {
                float4 rv = reinterpret_cast<const float4*>(&sm.rbuf[wv][j][0])[28];
                t3[j] = dot4(w, rv);
            }
        }
#pragma unroll
        for (int j = 0; j < 4; ++j) {
            out[(r0 + j) * 64 + lane] =
                fmaf(cf0[j], t0[j], fmaf(cf1[j], t1[j], fmaf(cf2[j], t2[j], t3[j])));
        }
    }
}

extern "C" void kernel_launch(void* const* d_in, const int* in_sizes, int n_in,
                              void* d_out, int out_size, void* d_ws, size_t ws_size,
                              hipStream_t stream) {
    const float* query = (const float*)d_in[0];
    const float* mem0  = (const float*)d_in[1];
    const float* mem1  = (const float*)d_in[2];
    const float* mem2  = (const float*)d_in[3];
    const float* Wp0   = (const float*)d_in[4];
    const float* bp0   = (const float*)d_in[5];
    const float* Wu0   = (const float*)d_in[6];
    const float* bu0   = (const float*)d_in[7];
    const float* Wp1   = (const float*)d_in[8];
    const float* bp1   = (const float*)d_in[9];
    const float* Wu1   = (const float*)d_in[10];
    const float* bu1   = (const float*)d_in[11];
    const float* Wp2   = (const float*)d_in[12];
    const float* bp2   = (const float*)d_in[13];
    const float* Wu2   = (const float*)d_in[14];
    const float* bu2   = (const float*)d_in[15];
    const float* Wc    = (const float*)d_in[16];
    const float* bc    = (const float*)d_in[17];
    float* waug = (float*)d_ws;   // 64*116 floats = 29696 B
    float* outp = (float*)d_out;

    prep_kernel<<<64, 128, 0, stream>>>(Wu0, Wu1, Wu2, bu0, bu1, bu2, Wc, bc, waug);
    retrieval_kernel<<<GRID1, 256, 0, stream>>>(query, mem0, mem1, mem2,
                                                Wp0, bp0, Wp1, bp1, Wp2, bp2,
                                                waug, outp);
}